// Round 12
// baseline (302.692 us; speedup 1.0000x reference)
//
#include <hip/hip_runtime.h>
#include <hip/hip_bf16.h>

// Problem constants: x [4,32,32,16,256] -> N=65536 rows, D=256
// embeddings [256, 4096] -> D=256, K=4096
#define NROWS 65536
#define DIM   256
#define KCB   4096
#define CHUNK 32                 // codebook cols per chunk (16KB)
#define NCH   (KCB / CHUNK)      // 128 chunks
#define NBUF  4                  // buffer ring depth
#define BUFB  16384              // bytes per buffer
#define NENH_BASE (NBUF * BUFB)  // nenh f32[4096] at end of LDS (16KB)

typedef __attribute__((ext_vector_type(8))) short bf16x8;  // 8 bf16, 4 VGPRs
typedef __attribute__((ext_vector_type(4))) float f32x4;

#define WAITV0 asm volatile("s_waitcnt vmcnt(0)" ::: "memory")
#define WAITV4 asm volatile("s_waitcnt vmcnt(4)" ::: "memory")
#define WAITV8 asm volatile("s_waitcnt vmcnt(8)" ::: "memory")

__device__ inline short f2bf(float f) {
    __hip_bfloat16 h = __float2bfloat16(f);
    return *reinterpret_cast<short*>(&h);
}

// ---------------------------------------------------------------------------
// Prep 1: tiled transpose E[256][4096] -> ET32[4096][256] (f32) + ETbf (bf16)
// ---------------------------------------------------------------------------
__global__ void prep_transpose(const float* __restrict__ E,
                               float* __restrict__ ET32,
                               ushort* __restrict__ ETbf)
{
    __shared__ float tile[64][65];
    const int kb = blockIdx.x * 64;
    const int db = blockIdx.y * 64;
    const int lo = threadIdx.x & 63;
    const int hi = threadIdx.x >> 6;

#pragma unroll
    for (int i = 0; i < 16; ++i) {
        int d = i * 4 + hi;
        tile[lo][d] = E[(size_t)(db + d) * KCB + kb + lo];
    }
    __syncthreads();
#pragma unroll
    for (int i = 0; i < 16; ++i) {
        int k = i * 4 + hi;
        float v = tile[k][lo];
        size_t off = (size_t)(kb + k) * DIM + db + lo;
        ET32[off] = v;
        ETbf[off] = (ushort)f2bf(v);
    }
}

// ---------------------------------------------------------------------------
// Prep 2: nenh[k] = -0.5*||e_k||^2 (fp32-exact); score = sim + nenh.
// ---------------------------------------------------------------------------
__global__ void prep_enorm(const float* __restrict__ E, float* __restrict__ nenh)
{
    int k = blockIdx.x * 256 + threadIdx.x;
    float s = 0.0f;
#pragma unroll 8
    for (int d = 0; d < DIM; ++d) {
        float v = E[(size_t)d * KCB + k];
        s = fmaf(v, v, s);
    }
    nenh[k] = -0.5f * s;
}

// ---------------------------------------------------------------------------
// vq_argmin: 256-thread blocks, 4 waves = 2 row-groups (64 rows) x 2
// col-halves (16 cols of each 32-col chunk). 128 rows/block, grid 512 =
// 2 blocks/CU = 8 waves/CU = 2 waves/SIMD. 512-thread blocks are capped at
// 128 arch VGPRs by the compiler (R10/R11: ~120-reg spill, 110MB scratch);
// 256-thread blocks + __launch_bounds__(256,2) budget 256 VGPRs.
// LDS-read/CU/chunk = 8 waves x 8KB = 64KB (~770cyc) < MFMA 1242cyc ->
// MFMA-bound. Ring-4 LDS + counted vmcnt + 1-chunk register read-ahead.
// Argmax via packed monotonic keys: key = ord(f32 score) with low 12 bits
// replaced by col (score perturbation <= 2^-6 at score exponent ~5 —
// negligible vs the ~0.3 bf16 noise) -> 1 v_max_u32 per output, no bidx.
// LDS map/block: [0, 64K) ring; [64K, 80K) nenh. 2 x 80KB = 160KB/CU exact.
// ---------------------------------------------------------------------------
__shared__ char lds_raw[NBUF * BUFB + 16384];

// Stage chunk ct (32 cols x 512B = 16KB) into buffer BUF. 4 waves x 4 issues
// x 1KB. LDS dest linear; XOR swizzle (slot ^= col&7) pre-applied to the
// per-lane GLOBAL source offset (both-sides rule, verified R4-R11).
template <int BUF>
__device__ __forceinline__ void stage_chunk(
    const char* __restrict__ etb, const int (&soff)[4], int wave, int ct)
{
    const char* base = etb + (size_t)ct * (CHUNK * 512);
#pragma unroll
    for (int j = 0; j < 4; ++j) {
        __builtin_amdgcn_global_load_lds(
            (const __attribute__((address_space(1))) unsigned*)(base + soff[j]),
            (__attribute__((address_space(3))) unsigned*)
                (lds_raw + BUF * BUFB + wave * 4096 + j * 1024),
            16, 0, 0);
    }
}

// Read one fragment batch (this wave's 16-col half): 8x ds_read_b128 + nh.
// boffB includes h*8192; max imm = 3*16384 + 16368 = 65520 (fits 16-bit DS).
template <int BUF>
__device__ __forceinline__ void read_batch(
    const int (&boffB)[8], int nhbyte, bf16x8 (&bfr)[8], float& nh)
{
#pragma unroll
    for (int kc = 0; kc < 8; ++kc)
        bfr[kc] = *(const bf16x8*)(lds_raw + BUF * BUFB + boffB[kc]);
    nh = *(const float*)(lds_raw + NENH_BASE + nhbyte);
}

// 32 MFMA (4 independent acc chains, 64 rows) under setprio, then packed-key
// argmax (6 VALU/output). C/D: col = lane&15, row = (lane>>4)*4 + r.
__device__ __forceinline__ void mfma_cluster(
    const bf16x8 (&afrag)[4][8], const bf16x8 (&bfr)[8], float nh,
    unsigned (&best)[4][4], int col)
{
    f32x4 acc[4];
#pragma unroll
    for (int rt = 0; rt < 4; ++rt) acc[rt] = {nh, nh, nh, nh};
    __builtin_amdgcn_s_setprio(1);
#pragma unroll
    for (int kc = 0; kc < 8; ++kc)
#pragma unroll
        for (int rt = 0; rt < 4; ++rt)
            acc[rt] = __builtin_amdgcn_mfma_f32_16x16x32_bf16(
                afrag[rt][kc], bfr[kc], acc[rt], 0, 0, 0);
    __builtin_amdgcn_s_setprio(0);
#pragma unroll
    for (int rt = 0; rt < 4; ++rt)
#pragma unroll
        for (int r = 0; r < 4; ++r) {
            unsigned u = __float_as_uint(acc[rt][r]);
            unsigned key = u ^ ((unsigned)((int)u >> 31) | 0x80000000u);
            unsigned pk = (key & 0xFFFFF000u) | (unsigned)col;
            best[rt][r] = max(best[rt][r], pk);
        }
}

// One chunk: WAITV -> barrier -> stage(ct+3) -> read(ct+1)->nxt -> MFMA(cur).
// Invariant entering ct: outstanding = {ct+1(4), ct+2(4)} = 8. WAITV4
// retires ct+1 (read-ahead safe), leaves ct+2; stage ct+3 -> 8 again.
// Stage target (BUF+3)&3 disjoint from read bufs BUF, (BUF+1)&3.
template <int BUF, int WN, bool STG, bool RA>
__device__ __forceinline__ void chunk_step(
    const char* __restrict__ etb, const int (&soff)[4], int wave, int ct,
    const int (&boffB)[8], int hc,
    const bf16x8 (&afrag)[4][8],
    bf16x8 (&cur)[8], float& nhc, bf16x8 (&nxt)[8], float& nhn,
    unsigned (&best)[4][4])
{
    if constexpr (WN == 4) { WAITV4; } else { WAITV0; }
    __builtin_amdgcn_s_barrier();
    __builtin_amdgcn_sched_barrier(0);
    if constexpr (STG) stage_chunk<(BUF + 3) & 3>(etb, soff, wave, ct + 3);
    if constexpr (RA)
        read_batch<(BUF + 1) & 3>(boffB, (ct + 1) * 128 + hc * 4, nxt, nhn);
    mfma_cluster(afrag, cur, nhc, best, ct * CHUNK + hc);
}

__global__ __launch_bounds__(256, 2)
void vq_argmin(const float* __restrict__ X,       // [65536][256] f32
               const ushort* __restrict__ ETbf,   // [4096][256] bf16
               const float* __restrict__ nenh,    // [4096] = -0.5*||e||^2
               int* __restrict__ idxout)          // [65536]
{
    const int tid  = threadIdx.x;
    const int lane = tid & 63;
    const int wave = tid >> 6;          // 0..3
    const int rg   = wave & 1;          // row-group (64 rows)
    const int h    = wave >> 1;         // col-half (16 cols of each chunk)
    const int l15  = lane & 15;
    const int g    = lane >> 4;         // 0..3
    const int m    = l15 & 7;           // read-side swizzle key
    const int hc   = h * 16 + l15;      // col within chunk
    const long rowbase = (long)blockIdx.x * 128 + rg * 64;
    const char* etb = (const char*)ETbf;

    // A fragments resident in VGPRs: lane holds A[row=l15][k=g*64+kc*8+j],
    // rows rowbase + rt*16 + l15, rt = 0..3 (64 rows/wave).
    bf16x8 afrag[4][8];
#pragma unroll
    for (int rt = 0; rt < 4; ++rt) {
        const float* xr = X + (rowbase + rt * 16 + l15) * DIM;
#pragma unroll
        for (int kc = 0; kc < 8; ++kc) {
            int k0 = g * 64 + kc * 8;
            float4 v0 = *(const float4*)(xr + k0);
            float4 v1 = *(const float4*)(xr + k0 + 4);
            bf16x8 f;
            f[0] = f2bf(v0.x); f[1] = f2bf(v0.y);
            f[2] = f2bf(v0.z); f[3] = f2bf(v0.w);
            f[4] = f2bf(v1.x); f[5] = f2bf(v1.y);
            f[6] = f2bf(v1.z); f[7] = f2bf(v1.w);
            afrag[rt][kc] = f;
        }
    }

    // Per-lane global source offsets for staging (XOR-swizzled, as R4-R11).
    int soff[4];
#pragma unroll
    for (int j = 0; j < 4; ++j) {
        const int o    = wave * 4096 + j * 1024 + lane * 16;
        const int col0 = o >> 9;           // 0..31 within chunk
        const int cph  = (o >> 4) & 31;    // physical 16B slot in row
        soff[j] = (col0 << 9) + ((cph ^ (col0 & 7)) << 4);
    }

    // LDS read offsets: this wave's half-tile (chunk-local col hc = h*16+l15,
    // byte base hc*512 = h*8192 + l15*512), slot (g*8+kc) ^ m (m = hc&7).
    int boffB[8];
#pragma unroll
    for (int kc = 0; kc < 8; ++kc)
        boffB[kc] = h * 8192 + l15 * 512 + ((((g << 3) + kc) ^ m) << 4);

    // Prologue staging: nenh (16KB; 4 issues/wave) + chunks 0,1,2 (4 each).
#pragma unroll
    for (int j = 0; j < 4; ++j) {
        int o = wave * 4096 + j * 1024 + lane * 16;
        __builtin_amdgcn_global_load_lds(
            (const __attribute__((address_space(1))) unsigned*)((const char*)nenh + o),
            (__attribute__((address_space(3))) unsigned*)
                (lds_raw + NENH_BASE + wave * 4096 + j * 1024),
            16, 0, 0);
    }
    stage_chunk<0>(etb, soff, wave, 0);
    stage_chunk<1>(etb, soff, wave, 1);
    stage_chunk<2>(etb, soff, wave, 2);

    unsigned best[4][4];
#pragma unroll
    for (int rt = 0; rt < 4; ++rt)
#pragma unroll
        for (int r = 0; r < 4; ++r) best[rt][r] = 0u;

    bf16x8 bA[8], bB[8];
    float nhA, nhB;

    // Prologue wait: 16 outstanding; retire nenh + chunk0, leave {c1,c2}=8.
    WAITV8;
    __builtin_amdgcn_s_barrier();
    __builtin_amdgcn_sched_barrier(0);
    read_batch<0>(boffB, hc * 4, bA, nhA);

    // Main loop: all 128 chunks; ct = 0..123 here, tail 124..127 below.
    for (int gq = 0; gq < 31; ++gq) {
        const int ct = gq * 4;
        chunk_step<0, 4, true, true>(etb, soff, wave, ct + 0, boffB, hc,
                                     afrag, bA, nhA, bB, nhB, best);
        chunk_step<1, 4, true, true>(etb, soff, wave, ct + 1, boffB, hc,
                                     afrag, bB, nhB, bA, nhA, best);
        chunk_step<2, 4, true, true>(etb, soff, wave, ct + 2, boffB, hc,
                                     afrag, bA, nhA, bB, nhB, best);
        chunk_step<3, 4, true, true>(etb, soff, wave, ct + 3, boffB, hc,
                                     afrag, bB, nhB, bA, nhA, best);
    }
    // Tail: 124 (stages 127), 125, 126 (drain for 127 read-ahead), 127.
    chunk_step<0, 4, true,  true >(etb, soff, wave, 124, boffB, hc,
                                   afrag, bA, nhA, bB, nhB, best);
    chunk_step<1, 4, false, true >(etb, soff, wave, 125, boffB, hc,
                                   afrag, bB, nhB, bA, nhA, best);
    chunk_step<2, 0, false, true >(etb, soff, wave, 126, boffB, hc,
                                   afrag, bA, nhA, bB, nhB, best);
    chunk_step<3, 0, false, false>(etb, soff, wave, 127, boffB, hc,
                                   afrag, bB, nhB, bA, nhA, best);

    // Per-wave reduce across the 16 lanes sharing a row (packed keys), then
    // cross-half merge via LDS (reuses ring buffer 0; all reads done).
    __syncthreads();
    unsigned* mrg = (unsigned*)lds_raw;   // [2][128] packed keys
#pragma unroll
    for (int rt = 0; rt < 4; ++rt) {
#pragma unroll
        for (int r = 0; r < 4; ++r) {
            unsigned pk = best[rt][r];
#pragma unroll
            for (int off = 1; off < 16; off <<= 1)
                pk = max(pk, (unsigned)__shfl_xor((int)pk, off, 64));
            if (l15 == 0) {
                int row = rg * 64 + rt * 16 + g * 4 + r;   // 0..127
                mrg[h * 128 + row] = pk;
            }
        }
    }
    __syncthreads();
    if (tid < 128) {
        unsigned k = max(mrg[tid], mrg[128 + tid]);
        idxout[(long)blockIdx.x * 128 + tid] = (int)(k & 0xFFFu);
    }
}

// ---------------------------------------------------------------------------
// Gather nearest codebook rows (coalesced from ET32) + histogram
// ---------------------------------------------------------------------------
__global__ void vq_gather(const int* __restrict__ idxin,
                          const float* __restrict__ ET32,
                          float* __restrict__ out,
                          unsigned* __restrict__ counts)
{
    const int tid = threadIdx.x;
    const long n  = (long)blockIdx.x * 4 + (tid >> 6);
    const int d4  = tid & 63;
    const int idx = idxin[n];
    float4 v = *(const float4*)(ET32 + (size_t)idx * DIM + d4 * 4);
    *(float4*)(out + n * DIM + d4 * 4) = v;
    if (d4 == 0) atomicAdd(&counts[idx], 1u);
}

// ---------------------------------------------------------------------------
// Perplexity = exp(-sum p*log(p+1e-10)), p = counts/N
// ---------------------------------------------------------------------------
__global__ void vq_perplexity(const unsigned* __restrict__ counts, float* __restrict__ outp)
{
    __shared__ float wsum[4];
    const int tid = threadIdx.x;
    float s = 0.0f;
    for (int k = tid; k < KCB; k += 256) {
        float p = (float)counts[k] * (1.0f / (float)NROWS);
        s += p * logf(p + 1e-10f);
    }
#pragma unroll
    for (int off = 32; off >= 1; off >>= 1) s += __shfl_down(s, off, 64);
    if ((tid & 63) == 0) wsum[tid >> 6] = s;
    __syncthreads();
    if (tid == 0) outp[0] = expf(-(wsum[0] + wsum[1] + wsum[2] + wsum[3]));
}

// ---------------------------------------------------------------------------
extern "C" void kernel_launch(void* const* d_in, const int* in_sizes, int n_in,
                              void* d_out, int out_size, void* d_ws, size_t ws_size,
                              hipStream_t stream)
{
    const float* X = (const float*)d_in[0];
    const float* E = (const float*)d_in[1];
    float* out = (float*)d_out;

    char* ws = (char*)d_ws;
    float*    ET32   = (float*)ws;                                   // 4 MB
    ushort*   ETbf   = (ushort*)(ws + (size_t)KCB * DIM * 4);        // 2 MB
    float*    nenh   = (float*)(ws + (size_t)KCB * DIM * 6);         // 16 KB
    int*      idxbuf = (int*)(ws + (size_t)KCB * DIM * 6 + KCB * 4); // 256 KB
    unsigned* counts = (unsigned*)(ws + (size_t)KCB * DIM * 6 + KCB * 4 + NROWS * 4); // 16 KB

    hipMemsetAsync(counts, 0, KCB * sizeof(unsigned), stream);

    prep_transpose<<<dim3(KCB / 64, DIM / 64), dim3(256), 0, stream>>>(E, ET32, ETbf);
    prep_enorm<<<KCB / 256, dim3(256), 0, stream>>>(E, nenh);
    vq_argmin<<<NROWS / 128, dim3(256), 0, stream>>>(X, ETbf, nenh, idxbuf);
    vq_gather<<<NROWS / 4, dim3(256), 0, stream>>>(idxbuf, ET32, out, counts);
    vq_perplexity<<<1, dim3(256), 0, stream>>>(counts, out + (size_t)NROWS * DIM);
}

// Round 13
// 184.245 us; speedup vs baseline: 1.6429x; 1.6429x over previous
//
#include <hip/hip_runtime.h>
#include <hip/hip_bf16.h>

// Problem constants: x [4,32,32,16,256] -> N=65536 rows, D=256
// embeddings [256, 4096] -> D=256, K=4096
#define NROWS 65536
#define DIM   256
#define KCB   4096
#define CHUNK 32                 // codebook cols per chunk (16KB)
#define NCH   (KCB / CHUNK)      // 128 chunks
#define NBUF  4                  // buffer ring depth
#define BUFB  16384              // bytes per buffer
#define NENH_BASE (NBUF * BUFB)  // nenh f32[4096] at end of LDS (16KB)

typedef __attribute__((ext_vector_type(8))) short bf16x8;  // 8 bf16, 4 VGPRs
typedef __attribute__((ext_vector_type(4))) float f32x4;

#define WAITV0 asm volatile("s_waitcnt vmcnt(0)" ::: "memory")
#define WAITV4 asm volatile("s_waitcnt vmcnt(4)" ::: "memory")
#define WAITV8 asm volatile("s_waitcnt vmcnt(8)" ::: "memory")

__device__ inline short f2bf(float f) {
    __hip_bfloat16 h = __float2bfloat16(f);
    return *reinterpret_cast<short*>(&h);
}

// ---------------------------------------------------------------------------
// Prep 1: tiled transpose E[256][4096] -> ET32[4096][256] (f32) + ETbf (bf16)
// ---------------------------------------------------------------------------
__global__ void prep_transpose(const float* __restrict__ E,
                               float* __restrict__ ET32,
                               ushort* __restrict__ ETbf)
{
    __shared__ float tile[64][65];
    const int kb = blockIdx.x * 64;
    const int db = blockIdx.y * 64;
    const int lo = threadIdx.x & 63;
    const int hi = threadIdx.x >> 6;

#pragma unroll
    for (int i = 0; i < 16; ++i) {
        int d = i * 4 + hi;
        tile[lo][d] = E[(size_t)(db + d) * KCB + kb + lo];
    }
    __syncthreads();
#pragma unroll
    for (int i = 0; i < 16; ++i) {
        int k = i * 4 + hi;
        float v = tile[k][lo];
        size_t off = (size_t)(kb + k) * DIM + db + lo;
        ET32[off] = v;
        ETbf[off] = (ushort)f2bf(v);
    }
}

// ---------------------------------------------------------------------------
// Prep 2: nenh[k] = -0.5*||e_k||^2 (fp32-exact); score = sim + nenh.
// ---------------------------------------------------------------------------
__global__ void prep_enorm(const float* __restrict__ E, float* __restrict__ nenh)
{
    int k = blockIdx.x * 256 + threadIdx.x;
    float s = 0.0f;
#pragma unroll 8
    for (int d = 0; d < DIM; ++d) {
        float v = E[(size_t)d * KCB + k];
        s = fmaf(v, v, s);
    }
    nenh[k] = -0.5f * s;
}

// ---------------------------------------------------------------------------
// vq_argmin: 256-thread blocks, 4 waves = 2 row-groups (64 rows) x 2
// col-halves; 128 rows/block; grid 512 = 2 blocks/CU = 2 waves/SIMD.
// REGISTER BUDGET (R10-R12 lesson): guaranteed 2 waves/SIMD => <=256
// unified VGPR/wave, arch half pinned at 128. Demand must stay ~<=220:
// afrag 128 + bfr 32 + acc 16 + best 16 + misc ~25. The R7-style register
// read-ahead set (+33) is what pushed R10-R12 into ~110MB/chunk spill —
// dropped here; latency hiding falls to 2-wave TLP + ring-4 counted vmcnt
// (stages stay 2 chunks in flight; no setprio — m190 null for lockstep).
// LDS-read/CU/chunk = 8 waves x 8KB = 64KB (~776cyc) + MFMA 1242cyc.
// LDS map/block: [0,64K) ring; [64K,80K) nenh. 2 x 80KB = 160KB/CU exact.
// ---------------------------------------------------------------------------
__shared__ char lds_raw[NBUF * BUFB + 16384];

// Stage chunk ct (32 cols x 512B = 16KB) into buffer BUF. 4 waves x 4 issues
// x 1KB. LDS dest linear; XOR swizzle (slot ^= col&7) pre-applied to the
// per-lane GLOBAL source offset (both-sides rule, verified R4-R12).
template <int BUF>
__device__ __forceinline__ void stage_chunk(
    const char* __restrict__ etb, const int (&soff)[4], int wave, int ct)
{
    const char* base = etb + (size_t)ct * (CHUNK * 512);
#pragma unroll
    for (int j = 0; j < 4; ++j) {
        __builtin_amdgcn_global_load_lds(
            (const __attribute__((address_space(1))) unsigned*)(base + soff[j]),
            (__attribute__((address_space(3))) unsigned*)
                (lds_raw + BUF * BUFB + wave * 4096 + j * 1024),
            16, 0, 0);
    }
}

// Read one fragment batch (this wave's 16-col half): 8x ds_read_b128 + nh.
// boffB includes h*8192; max imm = 3*16384 + 16368 = 65520 (fits 16-bit DS).
template <int BUF>
__device__ __forceinline__ void read_batch(
    const int (&boffB)[8], int nhbyte, bf16x8 (&bfr)[8], float& nh)
{
#pragma unroll
    for (int kc = 0; kc < 8; ++kc)
        bfr[kc] = *(const bf16x8*)(lds_raw + BUF * BUFB + boffB[kc]);
    nh = *(const float*)(lds_raw + NENH_BASE + nhbyte);
}

// 32 MFMA (4 independent acc chains, 64 rows), then packed-key argmax.
// key = ord(f32 score), low 12 bits replaced by col (perturbation <=2^-6,
// negligible vs ~0.3 bf16 noise). C/D: col = lane&15, row = (lane>>4)*4+r.
__device__ __forceinline__ void mfma_cluster(
    const bf16x8 (&afrag)[4][8], const bf16x8 (&bfr)[8], float nh,
    unsigned (&best)[4][4], int col)
{
    f32x4 acc[4];
#pragma unroll
    for (int rt = 0; rt < 4; ++rt) acc[rt] = {nh, nh, nh, nh};
#pragma unroll
    for (int kc = 0; kc < 8; ++kc)
#pragma unroll
        for (int rt = 0; rt < 4; ++rt)
            acc[rt] = __builtin_amdgcn_mfma_f32_16x16x32_bf16(
                afrag[rt][kc], bfr[kc], acc[rt], 0, 0, 0);
#pragma unroll
    for (int rt = 0; rt < 4; ++rt)
#pragma unroll
        for (int r = 0; r < 4; ++r) {
            unsigned u = __float_as_uint(acc[rt][r]);
            unsigned key = u ^ ((unsigned)((int)u >> 31) | 0x80000000u);
            unsigned pk = (key & 0xFFFFF000u) | (unsigned)col;
            best[rt][r] = max(best[rt][r], pk);
        }
}

// One chunk: WAITV -> barrier -> stage(ct+3) -> read(ct) -> MFMA(ct).
// vmcnt trace (4 issues per chunk stage, nenh+c0,c1,c2 staged in prologue):
// entering ct, outstanding = {ct(4), ct+1(4), ct+2(4)} = 12 (+4 nenh at
// ct=0, counted in its oldest-12... at ct=0: {nenh4,c0 4,c1 4,c2 4}=16,
// WAITV8 retires nenh+c0 ✓). Steady WAITV8 retires ct, leaves 8; stage
// ct+3 -> 12 again. Tail: 125 WAITV8 (12->8), 126 WAITV4, 127 WAITV0.
// Stage target (ct+3)&3 = (ct-1)&3 is the buffer read in chunk ct-1; the
// barrier at ct's top guarantees all waves finished those reads.
template <int BUF, int WN, bool STG>
__device__ __forceinline__ void chunk_step(
    const char* __restrict__ etb, const int (&soff)[4], int wave, int ct,
    const int (&boffB)[8], int hc,
    const bf16x8 (&afrag)[4][8], unsigned (&best)[4][4])
{
    if constexpr (WN == 8) { WAITV8; }
    else if constexpr (WN == 4) { WAITV4; }
    else { WAITV0; }
    __builtin_amdgcn_s_barrier();
    __builtin_amdgcn_sched_barrier(0);
    if constexpr (STG) stage_chunk<(BUF + 3) & 3>(etb, soff, wave, ct + 3);
    bf16x8 bfr[8];
    float nh;
    read_batch<BUF>(boffB, ct * 128 + hc * 4, bfr, nh);
    mfma_cluster(afrag, bfr, nh, best, ct * CHUNK + hc);
}

__global__ __launch_bounds__(256, 2)
void vq_argmin(const float* __restrict__ X,       // [65536][256] f32
               const ushort* __restrict__ ETbf,   // [4096][256] bf16
               const float* __restrict__ nenh,    // [4096] = -0.5*||e||^2
               int* __restrict__ idxout)          // [65536]
{
    const int tid  = threadIdx.x;
    const int lane = tid & 63;
    const int wave = tid >> 6;          // 0..3
    const int rg   = wave & 1;          // row-group (64 rows)
    const int h    = wave >> 1;         // col-half (16 cols of each chunk)
    const int l15  = lane & 15;
    const int g    = lane >> 4;         // 0..3
    const int m    = l15 & 7;           // read-side swizzle key
    const int hc   = h * 16 + l15;      // col within chunk
    const long rowbase = (long)blockIdx.x * 128 + rg * 64;
    const char* etb = (const char*)ETbf;

    // A fragments resident in VGPRs: lane holds A[row=l15][k=g*64+kc*8+j],
    // rows rowbase + rt*16 + l15, rt = 0..3 (64 rows/wave).
    bf16x8 afrag[4][8];
#pragma unroll
    for (int rt = 0; rt < 4; ++rt) {
        const float* xr = X + (rowbase + rt * 16 + l15) * DIM;
#pragma unroll
        for (int kc = 0; kc < 8; ++kc) {
            int k0 = g * 64 + kc * 8;
            float4 v0 = *(const float4*)(xr + k0);
            float4 v1 = *(const float4*)(xr + k0 + 4);
            bf16x8 f;
            f[0] = f2bf(v0.x); f[1] = f2bf(v0.y);
            f[2] = f2bf(v0.z); f[3] = f2bf(v0.w);
            f[4] = f2bf(v1.x); f[5] = f2bf(v1.y);
            f[6] = f2bf(v1.z); f[7] = f2bf(v1.w);
            afrag[rt][kc] = f;
        }
    }

    // Per-lane global source offsets for staging (XOR-swizzled, as R4-R12).
    int soff[4];
#pragma unroll
    for (int j = 0; j < 4; ++j) {
        const int o    = wave * 4096 + j * 1024 + lane * 16;
        const int col0 = o >> 9;           // 0..31 within chunk
        const int cph  = (o >> 4) & 31;    // physical 16B slot in row
        soff[j] = (col0 << 9) + ((cph ^ (col0 & 7)) << 4);
    }

    // LDS read offsets: this wave's half-tile (chunk-local col hc = h*16+l15,
    // byte base hc*512 = h*8192 + l15*512), slot (g*8+kc) ^ m (m = hc&7).
    int boffB[8];
#pragma unroll
    for (int kc = 0; kc < 8; ++kc)
        boffB[kc] = h * 8192 + l15 * 512 + ((((g << 3) + kc) ^ m) << 4);

    // Prologue staging: nenh (16KB; 4 issues/wave) + chunks 0,1,2 (4 each).
#pragma unroll
    for (int j = 0; j < 4; ++j) {
        int o = wave * 4096 + j * 1024 + lane * 16;
        __builtin_amdgcn_global_load_lds(
            (const __attribute__((address_space(1))) unsigned*)((const char*)nenh + o),
            (__attribute__((address_space(3))) unsigned*)
                (lds_raw + NENH_BASE + wave * 4096 + j * 1024),
            16, 0, 0);
    }
    stage_chunk<0>(etb, soff, wave, 0);
    stage_chunk<1>(etb, soff, wave, 1);
    stage_chunk<2>(etb, soff, wave, 2);

    unsigned best[4][4];
#pragma unroll
    for (int rt = 0; rt < 4; ++rt)
#pragma unroll
        for (int r = 0; r < 4; ++r) best[rt][r] = 0u;

    // Main loop: all 128 chunks; ct = 0..123 here, tail 124..127 below.
    for (int gq = 0; gq < 31; ++gq) {
        const int ct = gq * 4;
        chunk_step<0, 8, true>(etb, soff, wave, ct + 0, boffB, hc, afrag, best);
        chunk_step<1, 8, true>(etb, soff, wave, ct + 1, boffB, hc, afrag, best);
        chunk_step<2, 8, true>(etb, soff, wave, ct + 2, boffB, hc, afrag, best);
        chunk_step<3, 8, true>(etb, soff, wave, ct + 3, boffB, hc, afrag, best);
    }
    // Tail: 124 (stages 127), then drain 8 -> 4 -> 0.
    chunk_step<0, 8, true >(etb, soff, wave, 124, boffB, hc, afrag, best);
    chunk_step<1, 8, false>(etb, soff, wave, 125, boffB, hc, afrag, best);
    chunk_step<2, 4, false>(etb, soff, wave, 126, boffB, hc, afrag, best);
    chunk_step<3, 0, false>(etb, soff, wave, 127, boffB, hc, afrag, best);

    // Per-wave reduce across the 16 lanes sharing a row (packed keys), then
    // cross-half merge via LDS (reuses ring buffer 0; all reads done).
    __syncthreads();
    unsigned* mrg = (unsigned*)lds_raw;   // [2][128] packed keys
#pragma unroll
    for (int rt = 0; rt < 4; ++rt) {
#pragma unroll
        for (int r = 0; r < 4; ++r) {
            unsigned pk = best[rt][r];
#pragma unroll
            for (int off = 1; off < 16; off <<= 1)
                pk = max(pk, (unsigned)__shfl_xor((int)pk, off, 64));
            if (l15 == 0) {
                int row = rg * 64 + rt * 16 + g * 4 + r;   // 0..127
                mrg[h * 128 + row] = pk;
            }
        }
    }
    __syncthreads();
    if (tid < 128) {
        unsigned k = max(mrg[tid], mrg[128 + tid]);
        idxout[(long)blockIdx.x * 128 + tid] = (int)(k & 0xFFFu);
    }
}

// ---------------------------------------------------------------------------
// Gather nearest codebook rows (coalesced from ET32) + histogram
// ---------------------------------------------------------------------------
__global__ void vq_gather(const int* __restrict__ idxin,
                          const float* __restrict__ ET32,
                          float* __restrict__ out,
                          unsigned* __restrict__ counts)
{
    const int tid = threadIdx.x;
    const long n  = (long)blockIdx.x * 4 + (tid >> 6);
    const int d4  = tid & 63;
    const int idx = idxin[n];
    float4 v = *(const float4*)(ET32 + (size_t)idx * DIM + d4 * 4);
    *(float4*)(out + n * DIM + d4 * 4) = v;
    if (d4 == 0) atomicAdd(&counts[idx], 1u);
}

// ---------------------------------------------------------------------------
// Perplexity = exp(-sum p*log(p+1e-10)), p = counts/N
// ---------------------------------------------------------------------------
__global__ void vq_perplexity(const unsigned* __restrict__ counts, float* __restrict__ outp)
{
    __shared__ float wsum[4];
    const int tid = threadIdx.x;
    float s = 0.0f;
    for (int k = tid; k < KCB; k += 256) {
        float p = (float)counts[k] * (1.0f / (float)NROWS);
        s += p * logf(p + 1e-10f);
    }
#pragma unroll
    for (int off = 32; off >= 1; off >>= 1) s += __shfl_down(s, off, 64);
    if ((tid & 63) == 0) wsum[tid >> 6] = s;
    __syncthreads();
    if (tid == 0) outp[0] = expf(-(wsum[0] + wsum[1] + wsum[2] + wsum[3]));
}

// ---------------------------------------------------------------------------
extern "C" void kernel_launch(void* const* d_in, const int* in_sizes, int n_in,
                              void* d_out, int out_size, void* d_ws, size_t ws_size,
                              hipStream_t stream)
{
    const float* X = (const float*)d_in[0];
    const float* E = (const float*)d_in[1];
    float* out = (float*)d_out;

    char* ws = (char*)d_ws;
    float*    ET32   = (float*)ws;                                   // 4 MB
    ushort*   ETbf   = (ushort*)(ws + (size_t)KCB * DIM * 4);        // 2 MB
    float*    nenh   = (float*)(ws + (size_t)KCB * DIM * 6);         // 16 KB
    int*      idxbuf = (int*)(ws + (size_t)KCB * DIM * 6 + KCB * 4); // 256 KB
    unsigned* counts = (unsigned*)(ws + (size_t)KCB * DIM * 6 + KCB * 4 + NROWS * 4); // 16 KB

    hipMemsetAsync(counts, 0, KCB * sizeof(unsigned), stream);

    prep_transpose<<<dim3(KCB / 64, DIM / 64), dim3(256), 0, stream>>>(E, ET32, ETbf);
    prep_enorm<<<KCB / 256, dim3(256), 0, stream>>>(E, nenh);
    vq_argmin<<<NROWS / 128, dim3(256), 0, stream>>>(X, ETbf, nenh, idxbuf);
    vq_gather<<<NROWS / 4, dim3(256), 0, stream>>>(idxbuf, ET32, out, counts);
    vq_perplexity<<<1, dim3(256), 0, stream>>>(counts, out + (size_t)NROWS * DIM);
}

// Round 14
// 184.066 us; speedup vs baseline: 1.6445x; 1.0010x over previous
//
#include <hip/hip_runtime.h>
#include <hip/hip_bf16.h>

// Problem constants: x [4,32,32,16,256] -> N=65536 rows, D=256
// embeddings [256, 4096] -> D=256, K=4096
#define NROWS 65536
#define DIM   256
#define KCB   4096
#define CHUNK 32                 // codebook cols per chunk (16KB)
#define NCH   (KCB / CHUNK)      // 128 chunks
#define NBUF  4                  // buffer ring depth
#define BUFB  16384              // bytes per buffer
#define NENH_BASE (NBUF * BUFB)  // nenh f32[4096] at end of LDS (16KB)

typedef __attribute__((ext_vector_type(8))) short bf16x8;  // 8 bf16, 4 VGPRs
typedef __attribute__((ext_vector_type(4))) float f32x4;

#define WAITV0 asm volatile("s_waitcnt vmcnt(0)" ::: "memory")
#define WAITV4 asm volatile("s_waitcnt vmcnt(4)" ::: "memory")
#define WAITV8 asm volatile("s_waitcnt vmcnt(8)" ::: "memory")

__device__ inline short f2bf(float f) {
    __hip_bfloat16 h = __float2bfloat16(f);
    return *reinterpret_cast<short*>(&h);
}

// ---------------------------------------------------------------------------
// Prep 1: tiled transpose E[256][4096] -> ET32[4096][256] (f32) + ETbf (bf16)
// ---------------------------------------------------------------------------
__global__ void prep_transpose(const float* __restrict__ E,
                               float* __restrict__ ET32,
                               ushort* __restrict__ ETbf)
{
    __shared__ float tile[64][65];
    const int kb = blockIdx.x * 64;
    const int db = blockIdx.y * 64;
    const int lo = threadIdx.x & 63;
    const int hi = threadIdx.x >> 6;

#pragma unroll
    for (int i = 0; i < 16; ++i) {
        int d = i * 4 + hi;
        tile[lo][d] = E[(size_t)(db + d) * KCB + kb + lo];
    }
    __syncthreads();
#pragma unroll
    for (int i = 0; i < 16; ++i) {
        int k = i * 4 + hi;
        float v = tile[k][lo];
        size_t off = (size_t)(kb + k) * DIM + db + lo;
        ET32[off] = v;
        ETbf[off] = (ushort)f2bf(v);
    }
}

// ---------------------------------------------------------------------------
// Prep 2: nenh[k] = -0.5*||e_k||^2 (fp32-exact); score = sim + nenh.
// ---------------------------------------------------------------------------
__global__ void prep_enorm(const float* __restrict__ E, float* __restrict__ nenh)
{
    int k = blockIdx.x * 256 + threadIdx.x;
    float s = 0.0f;
#pragma unroll 8
    for (int d = 0; d < DIM; ++d) {
        float v = E[(size_t)d * KCB + k];
        s = fmaf(v, v, s);
    }
    nenh[k] = -0.5f * s;
}

// ---------------------------------------------------------------------------
// vq_argmin: 256-thread blocks, 4 waves = 2 row-groups (64 rows) x 2
// col-halves; 128 rows/block; grid 512 = 2 blocks/CU = 2 waves/SIMD.
// Register budget (R10-R12 lesson): no register read-ahead set; demand
// ~120 arch VGPR + acc/afrag in unified AGPR half, zero spill (R13 ✓).
// R13 FIX: nh (ds_read_b32) is now issued FIRST in read_batch. R13 read it
// LAST while mfma_cluster inits acc = nh -> first MFMA depended on the 9th
// LDS read = lgkmcnt(0) drain = full read/MFMA serialization (2657cyc/chunk,
// = MFMA 1242 + LDS 770 + writes + overhead summed). nh-first lets the
// compiler's progressive lgkm waits overlap bfr[1..7] under the kc=0 MFMAs.
// LDS map/block: [0,64K) ring; [64K,80K) nenh. 2 x 80KB = 160KB/CU exact.
// ---------------------------------------------------------------------------
__shared__ char lds_raw[NBUF * BUFB + 16384];

// Stage chunk ct (32 cols x 512B = 16KB) into buffer BUF. 4 waves x 4 issues
// x 1KB. LDS dest linear; XOR swizzle (slot ^= col&7) pre-applied to the
// per-lane GLOBAL source offset (both-sides rule, verified R4-R13).
template <int BUF>
__device__ __forceinline__ void stage_chunk(
    const char* __restrict__ etb, const int (&soff)[4], int wave, int ct)
{
    const char* base = etb + (size_t)ct * (CHUNK * 512);
#pragma unroll
    for (int j = 0; j < 4; ++j) {
        __builtin_amdgcn_global_load_lds(
            (const __attribute__((address_space(1))) unsigned*)(base + soff[j]),
            (__attribute__((address_space(3))) unsigned*)
                (lds_raw + BUF * BUFB + wave * 4096 + j * 1024),
            16, 0, 0);
    }
}

// Read one fragment batch (this wave's 16-col half): nh FIRST (its consumer
// is the acc init of every MFMA chain), then 8x ds_read_b128.
// boffB includes h*8192; max imm = 3*16384 + 16368 = 65520 (fits 16-bit DS).
template <int BUF>
__device__ __forceinline__ void read_batch(
    const int (&boffB)[8], int nhbyte, bf16x8 (&bfr)[8], float& nh)
{
    nh = *(const float*)(lds_raw + NENH_BASE + nhbyte);
#pragma unroll
    for (int kc = 0; kc < 8; ++kc)
        bfr[kc] = *(const bf16x8*)(lds_raw + BUF * BUFB + boffB[kc]);
}

// 32 MFMA (4 independent acc chains, 64 rows), then packed-key argmax.
// key = ord(f32 score), low 12 bits replaced by col (perturbation <=2^-6,
// negligible vs ~0.3 bf16 noise). C/D: col = lane&15, row = (lane>>4)*4+r.
__device__ __forceinline__ void mfma_cluster(
    const bf16x8 (&afrag)[4][8], const bf16x8 (&bfr)[8], float nh,
    unsigned (&best)[4][4], int col)
{
    f32x4 acc[4];
#pragma unroll
    for (int rt = 0; rt < 4; ++rt) acc[rt] = {nh, nh, nh, nh};
#pragma unroll
    for (int kc = 0; kc < 8; ++kc)
#pragma unroll
        for (int rt = 0; rt < 4; ++rt)
            acc[rt] = __builtin_amdgcn_mfma_f32_16x16x32_bf16(
                afrag[rt][kc], bfr[kc], acc[rt], 0, 0, 0);
#pragma unroll
    for (int rt = 0; rt < 4; ++rt)
#pragma unroll
        for (int r = 0; r < 4; ++r) {
            unsigned u = __float_as_uint(acc[rt][r]);
            unsigned key = u ^ ((unsigned)((int)u >> 31) | 0x80000000u);
            unsigned pk = (key & 0xFFFFF000u) | (unsigned)col;
            best[rt][r] = max(best[rt][r], pk);
        }
}

// One chunk: WAITV -> barrier -> stage(ct+3) -> read(ct) -> MFMA(ct).
// vmcnt trace (4 issues per chunk stage, nenh+c0,c1,c2 staged in prologue):
// entering ct=0: {nenh4, c0 4, c1 4, c2 4}=16, WAITV8 retires nenh+c0.
// Steady: entering ct, outstanding = {ct(4), ct+1(4), ct+2(4)} = 12;
// WAITV8 retires ct, leaves 8; stage ct+3 -> 12. Tail: 125 WAITV8,
// 126 WAITV4, 127 WAITV0. Stage target (ct+3)&3 = (ct-1)&3, whose reads
// finished before the barrier at ct's top (all waves).
template <int BUF, int WN, bool STG>
__device__ __forceinline__ void chunk_step(
    const char* __restrict__ etb, const int (&soff)[4], int wave, int ct,
    const int (&boffB)[8], int hc,
    const bf16x8 (&afrag)[4][8], unsigned (&best)[4][4])
{
    if constexpr (WN == 8) { WAITV8; }
    else if constexpr (WN == 4) { WAITV4; }
    else { WAITV0; }
    __builtin_amdgcn_s_barrier();
    __builtin_amdgcn_sched_barrier(0);
    if constexpr (STG) stage_chunk<(BUF + 3) & 3>(etb, soff, wave, ct + 3);
    bf16x8 bfr[8];
    float nh;
    read_batch<BUF>(boffB, ct * 128 + hc * 4, bfr, nh);
    mfma_cluster(afrag, bfr, nh, best, ct * CHUNK + hc);
}

__global__ __launch_bounds__(256, 2)
void vq_argmin(const float* __restrict__ X,       // [65536][256] f32
               const ushort* __restrict__ ETbf,   // [4096][256] bf16
               const float* __restrict__ nenh,    // [4096] = -0.5*||e||^2
               int* __restrict__ idxout)          // [65536]
{
    const int tid  = threadIdx.x;
    const int lane = tid & 63;
    const int wave = tid >> 6;          // 0..3
    const int rg   = wave & 1;          // row-group (64 rows)
    const int h    = wave >> 1;         // col-half (16 cols of each chunk)
    const int l15  = lane & 15;
    const int g    = lane >> 4;         // 0..3
    const int m    = l15 & 7;           // read-side swizzle key
    const int hc   = h * 16 + l15;      // col within chunk
    const long rowbase = (long)blockIdx.x * 128 + rg * 64;
    const char* etb = (const char*)ETbf;

    // A fragments resident in VGPRs: lane holds A[row=l15][k=g*64+kc*8+j],
    // rows rowbase + rt*16 + l15, rt = 0..3 (64 rows/wave).
    bf16x8 afrag[4][8];
#pragma unroll
    for (int rt = 0; rt < 4; ++rt) {
        const float* xr = X + (rowbase + rt * 16 + l15) * DIM;
#pragma unroll
        for (int kc = 0; kc < 8; ++kc) {
            int k0 = g * 64 + kc * 8;
            float4 v0 = *(const float4*)(xr + k0);
            float4 v1 = *(const float4*)(xr + k0 + 4);
            bf16x8 f;
            f[0] = f2bf(v0.x); f[1] = f2bf(v0.y);
            f[2] = f2bf(v0.z); f[3] = f2bf(v0.w);
            f[4] = f2bf(v1.x); f[5] = f2bf(v1.y);
            f[6] = f2bf(v1.z); f[7] = f2bf(v1.w);
            afrag[rt][kc] = f;
        }
    }

    // Per-lane global source offsets for staging (XOR-swizzled, as R4-R13).
    int soff[4];
#pragma unroll
    for (int j = 0; j < 4; ++j) {
        const int o    = wave * 4096 + j * 1024 + lane * 16;
        const int col0 = o >> 9;           // 0..31 within chunk
        const int cph  = (o >> 4) & 31;    // physical 16B slot in row
        soff[j] = (col0 << 9) + ((cph ^ (col0 & 7)) << 4);
    }

    // LDS read offsets: this wave's half-tile (chunk-local col hc = h*16+l15,
    // byte base hc*512 = h*8192 + l15*512), slot (g*8+kc) ^ m (m = hc&7).
    int boffB[8];
#pragma unroll
    for (int kc = 0; kc < 8; ++kc)
        boffB[kc] = h * 8192 + l15 * 512 + ((((g << 3) + kc) ^ m) << 4);

    // Prologue staging: nenh (16KB; 4 issues/wave) + chunks 0,1,2 (4 each).
#pragma unroll
    for (int j = 0; j < 4; ++j) {
        int o = wave * 4096 + j * 1024 + lane * 16;
        __builtin_amdgcn_global_load_lds(
            (const __attribute__((address_space(1))) unsigned*)((const char*)nenh + o),
            (__attribute__((address_space(3))) unsigned*)
                (lds_raw + NENH_BASE + wave * 4096 + j * 1024),
            16, 0, 0);
    }
    stage_chunk<0>(etb, soff, wave, 0);
    stage_chunk<1>(etb, soff, wave, 1);
    stage_chunk<2>(etb, soff, wave, 2);

    unsigned best[4][4];
#pragma unroll
    for (int rt = 0; rt < 4; ++rt)
#pragma unroll
        for (int r = 0; r < 4; ++r) best[rt][r] = 0u;

    // Main loop: all 128 chunks; ct = 0..123 here, tail 124..127 below.
    for (int gq = 0; gq < 31; ++gq) {
        const int ct = gq * 4;
        chunk_step<0, 8, true>(etb, soff, wave, ct + 0, boffB, hc, afrag, best);
        chunk_step<1, 8, true>(etb, soff, wave, ct + 1, boffB, hc, afrag, best);
        chunk_step<2, 8, true>(etb, soff, wave, ct + 2, boffB, hc, afrag, best);
        chunk_step<3, 8, true>(etb, soff, wave, ct + 3, boffB, hc, afrag, best);
    }
    // Tail: 124 (stages 127), then drain 8 -> 4 -> 0.
    chunk_step<0, 8, true >(etb, soff, wave, 124, boffB, hc, afrag, best);
    chunk_step<1, 8, false>(etb, soff, wave, 125, boffB, hc, afrag, best);
    chunk_step<2, 4, false>(etb, soff, wave, 126, boffB, hc, afrag, best);
    chunk_step<3, 0, false>(etb, soff, wave, 127, boffB, hc, afrag, best);

    // Per-wave reduce across the 16 lanes sharing a row (packed keys), then
    // cross-half merge via LDS (reuses ring buffer 0; all reads done).
    __syncthreads();
    unsigned* mrg = (unsigned*)lds_raw;   // [2][128] packed keys
#pragma unroll
    for (int rt = 0; rt < 4; ++rt) {
#pragma unroll
        for (int r = 0; r < 4; ++r) {
            unsigned pk = best[rt][r];
#pragma unroll
            for (int off = 1; off < 16; off <<= 1)
                pk = max(pk, (unsigned)__shfl_xor((int)pk, off, 64));
            if (l15 == 0) {
                int row = rg * 64 + rt * 16 + g * 4 + r;   // 0..127
                mrg[h * 128 + row] = pk;
            }
        }
    }
    __syncthreads();
    if (tid < 128) {
        unsigned k = max(mrg[tid], mrg[128 + tid]);
        idxout[(long)blockIdx.x * 128 + tid] = (int)(k & 0xFFFu);
    }
}

// ---------------------------------------------------------------------------
// Gather nearest codebook rows (coalesced from ET32) + histogram
// ---------------------------------------------------------------------------
__global__ void vq_gather(const int* __restrict__ idxin,
                          const float* __restrict__ ET32,
                          float* __restrict__ out,
                          unsigned* __restrict__ counts)
{
    const int tid = threadIdx.x;
    const long n  = (long)blockIdx.x * 4 + (tid >> 6);
    const int d4  = tid & 63;
    const int idx = idxin[n];
    float4 v = *(const float4*)(ET32 + (size_t)idx * DIM + d4 * 4);
    *(float4*)(out + n * DIM + d4 * 4) = v;
    if (d4 == 0) atomicAdd(&counts[idx], 1u);
}

// ---------------------------------------------------------------------------
// Perplexity = exp(-sum p*log(p+1e-10)), p = counts/N
// ---------------------------------------------------------------------------
__global__ void vq_perplexity(const unsigned* __restrict__ counts, float* __restrict__ outp)
{
    __shared__ float wsum[4];
    const int tid = threadIdx.x;
    float s = 0.0f;
    for (int k = tid; k < KCB; k += 256) {
        float p = (float)counts[k] * (1.0f / (float)NROWS);
        s += p * logf(p + 1e-10f);
    }
#pragma unroll
    for (int off = 32; off >= 1; off >>= 1) s += __shfl_down(s, off, 64);
    if ((tid & 63) == 0) wsum[tid >> 6] = s;
    __syncthreads();
    if (tid == 0) outp[0] = expf(-(wsum[0] + wsum[1] + wsum[2] + wsum[3]));
}

// ---------------------------------------------------------------------------
extern "C" void kernel_launch(void* const* d_in, const int* in_sizes, int n_in,
                              void* d_out, int out_size, void* d_ws, size_t ws_size,
                              hipStream_t stream)
{
    const float* X = (const float*)d_in[0];
    const float* E = (const float*)d_in[1];
    float* out = (float*)d_out;

    char* ws = (char*)d_ws;
    float*    ET32   = (float*)ws;                                   // 4 MB
    ushort*   ETbf   = (ushort*)(ws + (size_t)KCB * DIM * 4);        // 2 MB
    float*    nenh   = (float*)(ws + (size_t)KCB * DIM * 6);         // 16 KB
    int*      idxbuf = (int*)(ws + (size_t)KCB * DIM * 6 + KCB * 4); // 256 KB
    unsigned* counts = (unsigned*)(ws + (size_t)KCB * DIM * 6 + KCB * 4 + NROWS * 4); // 16 KB

    hipMemsetAsync(counts, 0, KCB * sizeof(unsigned), stream);

    prep_transpose<<<dim3(KCB / 64, DIM / 64), dim3(256), 0, stream>>>(E, ET32, ETbf);
    prep_enorm<<<KCB / 256, dim3(256), 0, stream>>>(E, nenh);
    vq_argmin<<<NROWS / 128, dim3(256), 0, stream>>>(X, ETbf, nenh, idxbuf);
    vq_gather<<<NROWS / 4, dim3(256), 0, stream>>>(idxbuf, ET32, out, counts);
    vq_perplexity<<<1, dim3(256), 0, stream>>>(counts, out + (size_t)NROWS * DIM);
}